// Round 1
// baseline (411.974 us; speedup 1.0000x reference)
//
#include <hip/hip_runtime.h>
#include <hip/hip_bf16.h>

// out = x>0 ? 0.9*x + 0.1*tanh(x) : 0.5*tanh(x)
// fp32 in, fp32 out, N = 8192*8192 = 2^26 elements (divisible by 4).
// Memory-bound: 512 MiB total traffic -> ~85us floor at 6.3 TB/s.

__device__ __forceinline__ float fast_tanh(float x) {
    // tanh(x) = 1 - 2/(exp(2x)+1); saturates to +1 on overflow (e=inf -> 2/inf=0),
    // to -1 as e->0. No inf/inf NaN path.
    float e = __expf(2.0f * x);
    return 1.0f - 2.0f / (e + 1.0f);
}

__device__ __forceinline__ float act(float x) {
    float t = fast_tanh(x);
    return (x > 0.0f) ? fmaf(x, 0.9f, t * 0.1f) : t * 0.5f;
}

__global__ void __launch_bounds__(256)
SlowCustomActivation_88441966559493_kernel(const float* __restrict__ x,
                                           float* __restrict__ out,
                                           long long n4) {
    long long i = (long long)blockIdx.x * blockDim.x + threadIdx.x;
    if (i >= n4) return;
    const float4* __restrict__ x4 = (const float4*)x;
    float4* __restrict__ o4 = (float4*)out;
    float4 v = x4[i];
    float4 r;
    r.x = act(v.x);
    r.y = act(v.y);
    r.z = act(v.z);
    r.w = act(v.w);
    o4[i] = r;
}

extern "C" void kernel_launch(void* const* d_in, const int* in_sizes, int n_in,
                              void* d_out, int out_size, void* d_ws, size_t ws_size,
                              hipStream_t stream) {
    const float* x = (const float*)d_in[0];
    float* out = (float*)d_out;
    long long n = (long long)in_sizes[0];   // 67108864
    long long n4 = n >> 2;                  // 16777216 float4s
    int block = 256;
    long long grid = (n4 + block - 1) / block;  // 65536
    SlowCustomActivation_88441966559493_kernel<<<(dim3)(unsigned)grid, block, 0, stream>>>(x, out, n4);
}